// Round 1
// baseline (185.624 us; speedup 1.0000x reference)
//
#include <hip/hip_runtime.h>
#include <math.h>

#define QN 131072
#define NF 9
#define NH 64
#define NO 128
#define QT 128

__global__ __launch_bounds__(32)
void zero_acc_kernel(double* __restrict__ acc) {
  if (threadIdx.x < 2*NF) acc[threadIdx.x] = 0.0;
}

__device__ __forceinline__ double wred(double v) {
#pragma unroll
  for (int off = 32; off > 0; off >>= 1)
    v += __shfl_down(v, off, 64);
  return v;
}

__global__ __launch_bounds__(256)
void stats_kernel(const float* __restrict__ geom,
                  const float* __restrict__ lq,
                  const int* __restrict__ nidx,
                  const int* __restrict__ rsplit,
                  float* __restrict__ feat,
                  double* __restrict__ acc)
{
  const int t = threadIdx.x;
  const int q = blockIdx.x * 256 + t;

  float qx = lq[q*3+0], qy = lq[q*3+1], qz = lq[q*3+2];
  int s = rsplit[q], e = rsplit[q+1];
  int cnt = e - s;

  float sx=0.f, sy=0.f, sz=0.f;
  float sxx=0.f, sxy=0.f, sxz=0.f, syy=0.f, syz=0.f, szz=0.f;
  float sd=0.f, sd2=0.f;

  for (int i = s; i < e; ++i) {
    int id = nidx[i];
    const float* p = geom + (size_t)id * 3;
    float px = p[0], py = p[1], pz = p[2];
    sx += px; sy += py; sz += pz;
    sxx = fmaf(px,px,sxx); sxy = fmaf(px,py,sxy); sxz = fmaf(px,pz,sxz);
    syy = fmaf(py,py,syy); syz = fmaf(py,pz,syz); szz = fmaf(pz,pz,szz);
    float dx = px-qx, dy = py-qy, dz = pz-qz;
    float dd = fmaf(dx,dx,fmaf(dy,dy,dz*dz));
    sd2 += dd;
    sd += sqrtf(dd);
  }

  float denom = fmaxf((float)cnt, 1.0f);
  float inv = 1.0f / denom;
  float Davg = sd * inv;
  float EX2 = sd2 * inv;
  float Dvar = fmaxf(EX2 - Davg*Davg, 0.0f);
  float cx = sx*inv, cy = sy*inv, cz = sz*inv;

  // covariance (one-pass, promoted to double), then analytic 3x3 eigvals
  double dinv = (double)inv;
  double dcx = (double)cx, dcy = (double)cy, dcz = (double)cz;
  double a00 = (double)sxx*dinv - dcx*dcx;
  double a01 = (double)sxy*dinv - dcx*dcy;
  double a02 = (double)sxz*dinv - dcx*dcz;
  double a11 = (double)syy*dinv - dcy*dcy;
  double a12 = (double)syz*dinv - dcy*dcz;
  double a22 = (double)szz*dinv - dcz*dcz;

  double l0, l1, l2;
  {
    double p1 = a01*a01 + a02*a02 + a12*a12;
    double qm = (a00 + a11 + a22) * (1.0/3.0);
    double b00 = a00 - qm, b11 = a11 - qm, b22 = a22 - qm;
    double p2 = b00*b00 + b11*b11 + b22*b22 + 2.0*p1;
    if (p2 < 1e-26) {
      l0 = l1 = l2 = qm;
    } else {
      double p = sqrt(p2 * (1.0/6.0));
      double ip = 1.0 / p;
      double c00 = b00*ip, c11 = b11*ip, c22 = b22*ip;
      double c01 = a01*ip, c02 = a02*ip, c12 = a12*ip;
      double det = c00*(c11*c22 - c12*c12)
                 - c01*(c01*c22 - c12*c02)
                 + c02*(c01*c12 - c11*c02);
      double r = 0.5 * det;
      r = fmin(1.0, fmax(-1.0, r));
      double phi = acos(r) * (1.0/3.0);
      double tp = 2.0 * p;
      l0 = qm + tp * cos(phi);
      l2 = qm + tp * cos(phi + 2.0943951023931953); // +2pi/3
      l1 = 3.0*qm - l0 - l2;
    }
  }

  float ft[NF];
  if (cnt > 0) {
    ft[0] = (float)cnt;
    ft[1] = Davg;
    ft[2] = Dvar;
    ft[3] = cx - qx; ft[4] = cy - qy; ft[5] = cz - qz;
    ft[6] = (float)l0; ft[7] = (float)l1; ft[8] = (float)l2;
  } else {
#pragma unroll
    for (int f = 0; f < NF; ++f) ft[f] = 0.f;
  }

  float* fp = feat + (size_t)q * NF;
#pragma unroll
  for (int f = 0; f < NF; ++f) fp[f] = ft[f];

  // block reduction (double) of sum and sumsq per feature -> global atomics
  __shared__ double sacc[4][2*NF];
  int wid = t >> 6, lane = t & 63;
#pragma unroll
  for (int f = 0; f < NF; ++f) {
    double v = (double)ft[f];
    double s1 = wred(v);
    double s2 = wred(v*v);
    if (lane == 0) { sacc[wid][f] = s1; sacc[wid][NF+f] = s2; }
  }
  __syncthreads();
  if (t < 2*NF) {
    double ssum = sacc[0][t] + sacc[1][t] + sacc[2][t] + sacc[3][t];
    atomicAdd(&acc[t], ssum);
  }
}

__global__ __launch_bounds__(32)
void finalize_kernel(const double* __restrict__ acc, float* __restrict__ sb) {
  int f = threadIdx.x;
  if (f < NF) {
    double s = acc[f], s2 = acc[NF+f];
    const double Qd = (double)QN;
    double mean = s / Qd;
    double var = (s2 - s*s/Qd) / (Qd - 1.0);
    var = fmax(var, 0.0);
    double sd = sqrt(var);
    if (sd < 1e-6) sd = 1.0;
    double iscl = 1.0 / sd;
    sb[f] = (float)iscl;
    sb[NF+f] = (float)(-mean * iscl);
  }
}

__global__ __launch_bounds__(256)
void mlp_kernel(const float* __restrict__ feat,
                const float* __restrict__ sbg,
                const float* __restrict__ W1, const float* __restrict__ b1,
                const float* __restrict__ W2, const float* __restrict__ b2,
                float* __restrict__ out)
{
  __shared__ float sW1[NF*NH];
  __shared__ float sb1[NH];
  __shared__ float sW2[NH*NO];
  __shared__ float sb2[NO];
  __shared__ float ssc[NF], sbi[NF];
  __shared__ float sf[QT][12];
  __shared__ float sh[NH][QT];

  const int t = threadIdx.x;
  for (int i = t; i < NF*NH; i += 256) sW1[i] = W1[i];
  for (int i = t; i < NH*NO; i += 256) sW2[i] = W2[i];
  if (t < NH) sb1[t] = b1[t];
  if (t < NO) sb2[t] = b2[t];
  if (t < NF) { ssc[t] = sbg[t]; sbi[t] = sbg[NF+t]; }
  __syncthreads();

  const int qbase = blockIdx.x * QT;

  for (int i = t; i < QT*NF; i += 256) {
    int qq = i / NF, f = i - qq*NF;
    sf[qq][f] = fmaf(feat[(size_t)(qbase+qq)*NF + f], ssc[f], sbi[f]);
  }
  __syncthreads();

  // phase 1: h = relu(feat@W1+b1) -> sh[k][q] (transposed)
  {
    int jg = (t & 7) * 8;
    int q0 = t >> 3;
#pragma unroll
    for (int pass = 0; pass < 4; ++pass) {
      int qq = q0 + pass*32;
      float a[8];
#pragma unroll
      for (int j = 0; j < 8; ++j) a[j] = sb1[jg+j];
#pragma unroll
      for (int k = 0; k < NF; ++k) {
        float fv = sf[qq][k];
#pragma unroll
        for (int j = 0; j < 8; ++j)
          a[j] = fmaf(fv, sW1[k*NH + jg + j], a[j]);
      }
#pragma unroll
      for (int j = 0; j < 8; ++j)
        sh[jg+j][qq] = fmaxf(a[j], 0.f);
    }
  }
  __syncthreads();

  // phase 2: out = relu(h@W2+b2), 8 queries x 8 outputs per thread
  const int o0 = (t & 15) * 8;
  const int q0 = (t >> 4) * 8;
  float acc[8][8];
#pragma unroll
  for (int qi = 0; qi < 8; ++qi)
#pragma unroll
    for (int oi = 0; oi < 8; ++oi) acc[qi][oi] = 0.f;

#pragma unroll 4
  for (int k = 0; k < NH; ++k) {
    float4 w0 = *(const float4*)&sW2[k*NO + o0];
    float4 w1 = *(const float4*)&sW2[k*NO + o0 + 4];
    float4 h0 = *(const float4*)&sh[k][q0];
    float4 h1 = *(const float4*)&sh[k][q0 + 4];
    float wv[8] = {w0.x,w0.y,w0.z,w0.w,w1.x,w1.y,w1.z,w1.w};
    float hv[8] = {h0.x,h0.y,h0.z,h0.w,h1.x,h1.y,h1.z,h1.w};
#pragma unroll
    for (int qi = 0; qi < 8; ++qi)
#pragma unroll
      for (int oi = 0; oi < 8; ++oi)
        acc[qi][oi] = fmaf(hv[qi], wv[oi], acc[qi][oi]);
  }

#pragma unroll
  for (int qi = 0; qi < 8; ++qi) {
    size_t qrow = (size_t)(qbase + q0 + qi) * NO + o0;
    float4 v0, v1;
    v0.x = fmaxf(acc[qi][0] + sb2[o0+0], 0.f);
    v0.y = fmaxf(acc[qi][1] + sb2[o0+1], 0.f);
    v0.z = fmaxf(acc[qi][2] + sb2[o0+2], 0.f);
    v0.w = fmaxf(acc[qi][3] + sb2[o0+3], 0.f);
    v1.x = fmaxf(acc[qi][4] + sb2[o0+4], 0.f);
    v1.y = fmaxf(acc[qi][5] + sb2[o0+5], 0.f);
    v1.z = fmaxf(acc[qi][6] + sb2[o0+6], 0.f);
    v1.w = fmaxf(acc[qi][7] + sb2[o0+7], 0.f);
    *(float4*)&out[qrow]     = v0;
    *(float4*)&out[qrow + 4] = v1;
  }
}

extern "C" void kernel_launch(void* const* d_in, const int* in_sizes, int n_in,
                              void* d_out, int out_size, void* d_ws, size_t ws_size,
                              hipStream_t stream) {
  const float* geom = (const float*)d_in[0];
  const float* lq   = (const float*)d_in[1];
  const int*   nidx = (const int*)d_in[2];
  const int*   rspl = (const int*)d_in[3];
  const float* W1   = (const float*)d_in[4];
  const float* b1   = (const float*)d_in[5];
  const float* W2   = (const float*)d_in[6];
  const float* b2   = (const float*)d_in[7];
  float* out = (float*)d_out;

  float*  feat = (float*)d_ws;                                   // QN*NF floats
  double* acc  = (double*)((char*)d_ws + (size_t)QN*NF*sizeof(float)); // 18 doubles
  float*  sb   = (float*)(acc + 2*NF);                           // 18 floats

  zero_acc_kernel<<<1, 32, 0, stream>>>(acc);
  stats_kernel<<<QN/256, 256, 0, stream>>>(geom, lq, nidx, rspl, feat, acc);
  finalize_kernel<<<1, 32, 0, stream>>>(acc, sb);
  mlp_kernel<<<QN/QT, 256, 0, stream>>>(feat, sb, W1, b1, W2, b2, out);
}

// Round 2
// 173.765 us; speedup vs baseline: 1.0682x; 1.0682x over previous
//
#include <hip/hip_runtime.h>
#include <math.h>

#define QN 131072
#define NF 9
#define NH 64
#define NO 128
#define QT 128

// ---------------- pad geom to float4 + zero the accumulator ----------------
__global__ __launch_bounds__(256)
void pad_kernel(const float* __restrict__ geom, float4* __restrict__ g4, int nn,
                double* __restrict__ acc) {
  int i = blockIdx.x * 256 + threadIdx.x;
  if (i < nn) {
    const float* p = geom + (size_t)i * 3;
    g4[i] = make_float4(p[0], p[1], p[2], 0.f);
  }
  if (blockIdx.x == 0 && threadIdx.x < 2*NF) acc[threadIdx.x] = 0.0;
}

// ---------------- moments: 8 threads per query, coalesced int4 idx ----------
__global__ __launch_bounds__(256)
void moments_kernel(const float4* __restrict__ g4,
                    const float* __restrict__ lq,
                    const int* __restrict__ nidx,
                    const int* __restrict__ rsplit,
                    float4* __restrict__ mom)
{
  const int t = threadIdx.x;
  const int g = t >> 3;        // query slot within block (32 per block)
  const int j = t & 7;         // sub-thread within query
  const int q = blockIdx.x * 32 + g;

  const int s = rsplit[q];
  const int e = rsplit[q+1];

  const float qx = lq[q*3+0], qy = lq[q*3+1], qz = lq[q*3+2];

  // 4 neighbors per sub-thread; uniform CSR (K=32) -> s is 16B-aligned
  int4 id4 = *(const int4*)(nidx + s + j*4);

  float sx=0.f, sy=0.f, sz=0.f;
  float sxx=0.f, sxy=0.f, sxz=0.f, syy=0.f, syz=0.f, szz=0.f;
  float sd=0.f, sd2=0.f;

  int ids[4] = {id4.x, id4.y, id4.z, id4.w};
#pragma unroll
  for (int m = 0; m < 4; ++m) {
    if (s + j*4 + m < e) {
      float4 p = g4[ids[m]];
      sx += p.x; sy += p.y; sz += p.z;
      sxx = fmaf(p.x,p.x,sxx); sxy = fmaf(p.x,p.y,sxy); sxz = fmaf(p.x,p.z,sxz);
      syy = fmaf(p.y,p.y,syy); syz = fmaf(p.y,p.z,syz); szz = fmaf(p.z,p.z,szz);
      float dx = p.x-qx, dy = p.y-qy, dz = p.z-qz;
      float dd = fmaf(dx,dx,fmaf(dy,dy,dz*dz));
      sd2 += dd;
      sd += sqrtf(dd);
    }
  }

  // reduce 11 sums across the 8 sub-threads
#pragma unroll
  for (int msk = 1; msk < 8; msk <<= 1) {
    sx  += __shfl_xor(sx,  msk, 8);
    sy  += __shfl_xor(sy,  msk, 8);
    sz  += __shfl_xor(sz,  msk, 8);
    sxx += __shfl_xor(sxx, msk, 8);
    sxy += __shfl_xor(sxy, msk, 8);
    sxz += __shfl_xor(sxz, msk, 8);
    syy += __shfl_xor(syy, msk, 8);
    syz += __shfl_xor(syz, msk, 8);
    szz += __shfl_xor(szz, msk, 8);
    sd  += __shfl_xor(sd,  msk, 8);
    sd2 += __shfl_xor(sd2, msk, 8);
  }

  if (j == 0) {
    float cntf = (float)(e - s);
    float4* mp = mom + (size_t)q * 3;
    mp[0] = make_float4(sx, sy, sz, sd);
    mp[1] = make_float4(sd2, sxx, sxy, sxz);
    mp[2] = make_float4(syy, syz, szz, cntf);
  }
}

__device__ __forceinline__ double wred(double v) {
#pragma unroll
  for (int off = 32; off > 0; off >>= 1)
    v += __shfl_down(v, off, 64);
  return v;
}

// ---------------- features: dense eigen + global mean/var reduction ---------
__global__ __launch_bounds__(256)
void feat_kernel(const float4* __restrict__ mom,
                 const float* __restrict__ lq,
                 float* __restrict__ feat,
                 double* __restrict__ acc)
{
  const int t = threadIdx.x;
  const int q = blockIdx.x * 256 + t;

  const float4 m0 = mom[(size_t)q*3+0];
  const float4 m1 = mom[(size_t)q*3+1];
  const float4 m2 = mom[(size_t)q*3+2];
  const float sx=m0.x, sy=m0.y, sz=m0.z, sd=m0.w;
  const float sd2=m1.x, sxx=m1.y, sxy=m1.z, sxz=m1.w;
  const float syy=m2.x, syz=m2.y, szz=m2.z, cntf=m2.w;

  const float qx = lq[q*3+0], qy = lq[q*3+1], qz = lq[q*3+2];

  float denom = fmaxf(cntf, 1.0f);
  float inv = 1.0f / denom;
  float Davg = sd * inv;
  float EX2 = sd2 * inv;
  float Dvar = fmaxf(EX2 - Davg*Davg, 0.0f);
  float cx = sx*inv, cy = sy*inv, cz = sz*inv;

  double dinv = (double)inv;
  double dcx = (double)cx, dcy = (double)cy, dcz = (double)cz;
  double a00 = (double)sxx*dinv - dcx*dcx;
  double a01 = (double)sxy*dinv - dcx*dcy;
  double a02 = (double)sxz*dinv - dcx*dcz;
  double a11 = (double)syy*dinv - dcy*dcy;
  double a12 = (double)syz*dinv - dcy*dcz;
  double a22 = (double)szz*dinv - dcz*dcz;

  double l0, l1, l2;
  {
    double p1 = a01*a01 + a02*a02 + a12*a12;
    double qm = (a00 + a11 + a22) * (1.0/3.0);
    double b00 = a00 - qm, b11 = a11 - qm, b22 = a22 - qm;
    double p2 = b00*b00 + b11*b11 + b22*b22 + 2.0*p1;
    if (p2 < 1e-26) {
      l0 = l1 = l2 = qm;
    } else {
      double p = sqrt(p2 * (1.0/6.0));
      double ip = 1.0 / p;
      double c00 = b00*ip, c11 = b11*ip, c22 = b22*ip;
      double c01 = a01*ip, c02 = a02*ip, c12 = a12*ip;
      double det = c00*(c11*c22 - c12*c12)
                 - c01*(c01*c22 - c12*c02)
                 + c02*(c01*c12 - c11*c02);
      double r = 0.5 * det;
      r = fmin(1.0, fmax(-1.0, r));
      double phi = acos(r) * (1.0/3.0);
      double tp = 2.0 * p;
      l0 = qm + tp * cos(phi);
      l2 = qm + tp * cos(phi + 2.0943951023931953); // +2pi/3
      l1 = 3.0*qm - l0 - l2;
    }
  }

  float ft[NF];
  if (cntf > 0.f) {
    ft[0] = cntf;
    ft[1] = Davg;
    ft[2] = Dvar;
    ft[3] = cx - qx; ft[4] = cy - qy; ft[5] = cz - qz;
    ft[6] = (float)l0; ft[7] = (float)l1; ft[8] = (float)l2;
  } else {
#pragma unroll
    for (int f = 0; f < NF; ++f) ft[f] = 0.f;
  }

  float* fp = feat + (size_t)q * NF;
#pragma unroll
  for (int f = 0; f < NF; ++f) fp[f] = ft[f];

  __shared__ double sacc[4][2*NF];
  int wid = t >> 6, lane = t & 63;
#pragma unroll
  for (int f = 0; f < NF; ++f) {
    double v = (double)ft[f];
    double s1 = wred(v);
    double s2 = wred(v*v);
    if (lane == 0) { sacc[wid][f] = s1; sacc[wid][NF+f] = s2; }
  }
  __syncthreads();
  if (t < 2*NF) {
    double ssum = sacc[0][t] + sacc[1][t] + sacc[2][t] + sacc[3][t];
    atomicAdd(&acc[t], ssum);
  }
}

__global__ __launch_bounds__(32)
void finalize_kernel(const double* __restrict__ acc, float* __restrict__ sb) {
  int f = threadIdx.x;
  if (f < NF) {
    double s = acc[f], s2 = acc[NF+f];
    const double Qd = (double)QN;
    double mean = s / Qd;
    double var = (s2 - s*s/Qd) / (Qd - 1.0);
    var = fmax(var, 0.0);
    double sd = sqrt(var);
    if (sd < 1e-6) sd = 1.0;
    double iscl = 1.0 / sd;
    sb[f] = (float)iscl;
    sb[NF+f] = (float)(-mean * iscl);
  }
}

__global__ __launch_bounds__(256)
void mlp_kernel(const float* __restrict__ feat,
                const float* __restrict__ sbg,
                const float* __restrict__ W1, const float* __restrict__ b1,
                const float* __restrict__ W2, const float* __restrict__ b2,
                float* __restrict__ out)
{
  __shared__ float sW1[NF*NH];
  __shared__ float sb1[NH];
  __shared__ float sW2[NH*NO];
  __shared__ float sb2[NO];
  __shared__ float ssc[NF], sbi[NF];
  __shared__ float sf[QT][12];
  __shared__ float sh[NH][QT];

  const int t = threadIdx.x;
  for (int i = t; i < NF*NH; i += 256) sW1[i] = W1[i];
  for (int i = t; i < NH*NO; i += 256) sW2[i] = W2[i];
  if (t < NH) sb1[t] = b1[t];
  if (t < NO) sb2[t] = b2[t];
  if (t < NF) { ssc[t] = sbg[t]; sbi[t] = sbg[NF+t]; }
  __syncthreads();

  const int qbase = blockIdx.x * QT;

  for (int i = t; i < QT*NF; i += 256) {
    int qq = i / NF, f = i - qq*NF;
    sf[qq][f] = fmaf(feat[(size_t)(qbase+qq)*NF + f], ssc[f], sbi[f]);
  }
  __syncthreads();

  // phase 1: h = relu(feat@W1+b1) -> sh[k][q] (transposed)
  {
    int jg = (t & 7) * 8;
    int q0 = t >> 3;
#pragma unroll
    for (int pass = 0; pass < 4; ++pass) {
      int qq = q0 + pass*32;
      float a[8];
#pragma unroll
      for (int j = 0; j < 8; ++j) a[j] = sb1[jg+j];
#pragma unroll
      for (int k = 0; k < NF; ++k) {
        float fv = sf[qq][k];
#pragma unroll
        for (int j = 0; j < 8; ++j)
          a[j] = fmaf(fv, sW1[k*NH + jg + j], a[j]);
      }
#pragma unroll
      for (int j = 0; j < 8; ++j)
        sh[jg+j][qq] = fmaxf(a[j], 0.f);
    }
  }
  __syncthreads();

  // phase 2: out = relu(h@W2+b2), 8 queries x 8 outputs per thread
  const int o0 = (t & 15) * 8;
  const int q0 = (t >> 4) * 8;
  float acc[8][8];
#pragma unroll
  for (int qi = 0; qi < 8; ++qi)
#pragma unroll
    for (int oi = 0; oi < 8; ++oi) acc[qi][oi] = 0.f;

#pragma unroll 4
  for (int k = 0; k < NH; ++k) {
    float4 w0 = *(const float4*)&sW2[k*NO + o0];
    float4 w1 = *(const float4*)&sW2[k*NO + o0 + 4];
    float4 h0 = *(const float4*)&sh[k][q0];
    float4 h1 = *(const float4*)&sh[k][q0 + 4];
    float wv[8] = {w0.x,w0.y,w0.z,w0.w,w1.x,w1.y,w1.z,w1.w};
    float hv[8] = {h0.x,h0.y,h0.z,h0.w,h1.x,h1.y,h1.z,h1.w};
#pragma unroll
    for (int qi = 0; qi < 8; ++qi)
#pragma unroll
      for (int oi = 0; oi < 8; ++oi)
        acc[qi][oi] = fmaf(hv[qi], wv[oi], acc[qi][oi]);
  }

#pragma unroll
  for (int qi = 0; qi < 8; ++qi) {
    size_t qrow = (size_t)(qbase + q0 + qi) * NO + o0;
    float4 v0, v1;
    v0.x = fmaxf(acc[qi][0] + sb2[o0+0], 0.f);
    v0.y = fmaxf(acc[qi][1] + sb2[o0+1], 0.f);
    v0.z = fmaxf(acc[qi][2] + sb2[o0+2], 0.f);
    v0.w = fmaxf(acc[qi][3] + sb2[o0+3], 0.f);
    v1.x = fmaxf(acc[qi][4] + sb2[o0+4], 0.f);
    v1.y = fmaxf(acc[qi][5] + sb2[o0+5], 0.f);
    v1.z = fmaxf(acc[qi][6] + sb2[o0+6], 0.f);
    v1.w = fmaxf(acc[qi][7] + sb2[o0+7], 0.f);
    *(float4*)&out[qrow]     = v0;
    *(float4*)&out[qrow + 4] = v1;
  }
}

extern "C" void kernel_launch(void* const* d_in, const int* in_sizes, int n_in,
                              void* d_out, int out_size, void* d_ws, size_t ws_size,
                              hipStream_t stream) {
  const float* geom = (const float*)d_in[0];
  const float* lq   = (const float*)d_in[1];
  const int*   nidx = (const int*)d_in[2];
  const int*   rspl = (const int*)d_in[3];
  const float* W1   = (const float*)d_in[4];
  const float* b1   = (const float*)d_in[5];
  const float* W2   = (const float*)d_in[6];
  const float* b2   = (const float*)d_in[7];
  float* out = (float*)d_out;
  const int nn = in_sizes[0] / 3;

  // ws layout
  char* w = (char*)d_ws;
  float*  feat = (float*)w;                      w += (size_t)QN*NF*sizeof(float);   // 4.7 MB
  float4* g4   = (float4*)w;                     w += (size_t)nn*sizeof(float4);     // 3.2 MB
  float4* mom  = (float4*)w;                     w += (size_t)QN*3*sizeof(float4);   // 6.3 MB
  double* acc  = (double*)w;                     w += 2*NF*sizeof(double);
  float*  sb   = (float*)w;

  pad_kernel<<<(nn+255)/256, 256, 0, stream>>>(geom, g4, nn, acc);
  moments_kernel<<<QN/32, 256, 0, stream>>>(g4, lq, nidx, rspl, mom);
  feat_kernel<<<QN/256, 256, 0, stream>>>(mom, lq, feat, acc);
  finalize_kernel<<<1, 32, 0, stream>>>(acc, sb);
  mlp_kernel<<<QN/QT, 256, 0, stream>>>(feat, sb, W1, b1, W2, b2, out);
}